// Round 7
// baseline (119.097 us; speedup 1.0000x reference)
//
#include <hip/hip_runtime.h>
#include <math.h>
#include <stdint.h>

#define N 4096
#define D 512
#define C 128
#define ALPHA 0.0005f
#define NT_TILES 32                 // N/128
#define TRI (NT_TILES * (NT_TILES + 1) / 2)   // 528 count tiles
#define NTILE (TRI + N / 128)                 // + 32 CE tiles = 560
#define GRID_FUSED 1024                       // persistent blocks, 4/CU

typedef __bf16 bf16x8 __attribute__((ext_vector_type(8)));
typedef float f32x4 __attribute__((ext_vector_type(4)));

// Workgroup barrier WITHOUT the vmcnt(0) drain __syncthreads() emits.
// lgkmcnt(0) makes this wave's ds_writes visible before s_barrier; global
// loads to VGPRs (prefetch) stay in flight across it.
__device__ __forceinline__ void wg_barrier_lgkm() {
    asm volatile("s_waitcnt lgkmcnt(0)\n\ts_barrier" ::: "memory");
}

// ---------------------------------------------------------------------------
// prep: blocks [0,N/4)        : 4 rows/block, 1 wave/row. sq, dot0, xb, cnt=0
//       blocks [N/4,N/4+256)  : Wtb[n][k] = bf16(W[k][n]); first one zeroes qhead
// ---------------------------------------------------------------------------
__global__ __launch_bounds__(256) void prep_kernel(const float* __restrict__ x,
                                                   float* __restrict__ sq,
                                                   float* __restrict__ dot0,
                                                   __bf16* __restrict__ xb,
                                                   const float* __restrict__ W,
                                                   __bf16* __restrict__ Wtb,
                                                   unsigned* __restrict__ cnt,
                                                   unsigned* __restrict__ qhead) {
    if (blockIdx.x >= N / 4) {
        const int tid = (blockIdx.x - N / 4) * 256 + threadIdx.x;  // 0..D*C-1
        const int k = tid >> 7;
        const int n = tid & 127;
        Wtb[(size_t)n * D + k] = (__bf16)W[tid];
        if (blockIdx.x == N / 4 && threadIdx.x == 0) *qhead = 0u;
        return;
    }
    const int i = blockIdx.x * 4 + (threadIdx.x >> 6);
    const int l = threadIdx.x & 63;
    const float* xp = x + (size_t)i * D + l * 8;
    const float4 v0 = *(const float4*)(xp);
    const float4 v1 = *(const float4*)(xp + 4);
    const float4 u0 = *(const float4*)(x + l * 8);
    const float4 u1 = *(const float4*)(x + l * 8 + 4);
    float s1 = v0.x * v0.x + v0.y * v0.y + v0.z * v0.z + v0.w * v0.w
             + v1.x * v1.x + v1.y * v1.y + v1.z * v1.z + v1.w * v1.w;
    float s2 = v0.x * u0.x + v0.y * u0.y + v0.z * u0.z + v0.w * u0.w
             + v1.x * u1.x + v1.y * u1.y + v1.z * u1.z + v1.w * u1.w;
    bf16x8 o;
    o[0] = (__bf16)v0.x; o[1] = (__bf16)v0.y; o[2] = (__bf16)v0.z; o[3] = (__bf16)v0.w;
    o[4] = (__bf16)v1.x; o[5] = (__bf16)v1.y; o[6] = (__bf16)v1.z; o[7] = (__bf16)v1.w;
    *(bf16x8*)(xb + (size_t)i * D + l * 8) = o;
    for (int off = 32; off; off >>= 1) {
        s1 += __shfl_down(s1, off);
        s2 += __shfl_down(s2, off);
    }
    if (l == 0) { sq[i] = s1; dot0[i] = s2; cnt[i] = 0u; }
}

// ---------------------------------------------------------------------------
// fused_mfma (persistent, tile queue):
//   tiles [0,TRI)      : neighbor-count tile (ti,tj), tj>=ti, symmetric update
//   tiles [TRI,TRI+32) : CE tile (128 rows x 128 logits + log-softmax)
// 128x128 tile, BK=32, register-staged pipeline with NON-DRAINING barrier:
//   ds_write(regs k) ; global loads k+1 -> regs ; [lgkmcnt(0); s_barrier] ;
//   ds_read frags ; 16 MFMA.  Prefetch survives the barrier (no vmcnt drain).
// LDS slot swizzle keeps global loads coalesced and ds ops <=2-way banked.
// ---------------------------------------------------------------------------
__global__ __launch_bounds__(256) void fused_mfma(const __bf16* __restrict__ xb,
                                                  const __bf16* __restrict__ Wtb,
                                                  const float* __restrict__ sq,
                                                  const float* __restrict__ dot0,
                                                  const int* __restrict__ y,
                                                  const float* __restrict__ b,
                                                  unsigned* __restrict__ cnt,
                                                  float* __restrict__ lossrow,
                                                  unsigned* __restrict__ qhead) {
    __shared__ __bf16 Alds[2][128 * 32];
    __shared__ __bf16 Blds[2][128 * 32];
    __shared__ float rmax[128][2];
    __shared__ float rsum[128][2];
    __shared__ int bidS;
    const int t = threadIdx.x;
    const int w = t >> 6, l = t & 63;
    const int wy = w >> 1, wx = w & 1;
    const int kg = l >> 4, lr = l & 15;

    // staging geometry: 512 x 16B chunks per matrix per K-tile; 2 per thread.
    const int e0 = t, e1 = t + 256;
    const int r0 = e0 >> 2, c0 = e0 & 3;
    const int r1 = e1 >> 2, c1 = e1 & 3;
    const int sc0 = (c0 ^ (r0 & 3) ^ ((r0 >> 2) & 3)) & 3;
    const int sc1 = (c1 ^ (r1 & 3) ^ ((r1 >> 2) & 3)) & 3;

    for (;;) {
        if (t == 0) bidS = (int)atomicAdd(qhead, 1u);
        __syncthreads();
        const int bid = bidS;
        if (bid >= NTILE) break;

        const bool isCE = (bid >= TRI);
        int bi, bj;
        bool diag = false;
        const __bf16* Bbase;
        if (isCE) {
            bi = (bid - TRI) * 128;
            bj = 0;
            Bbase = Wtb;
        } else {
            int tj = (int)((sqrtf(8.f * (float)bid + 1.f) - 1.f) * 0.5f);
            while (tj * (tj + 1) / 2 > bid) --tj;
            while ((tj + 1) * (tj + 2) / 2 <= bid) ++tj;
            const int ti = bid - tj * (tj + 1) / 2;
            bi = ti * 128;
            bj = tj * 128;
            diag = (ti == tj);
            Bbase = xb + (size_t)bj * D;
        }
        const __bf16* Abase = xb + (size_t)bi * D;

        f32x4 acc[4][4];
        const f32x4 zero = {0.f, 0.f, 0.f, 0.f};
#pragma unroll
        for (int mt = 0; mt < 4; ++mt)
#pragma unroll
            for (int nt = 0; nt < 4; ++nt) acc[mt][nt] = zero;

        const __bf16* Ap0 = Abase + (size_t)r0 * D + sc0 * 8;
        const __bf16* Ap1 = Abase + (size_t)r1 * D + sc1 * 8;
        const __bf16* Bp0 = Bbase + (size_t)r0 * D + sc0 * 8;
        const __bf16* Bp1 = Bbase + (size_t)r1 * D + sc1 * 8;

        // prologue: load K-tile 0 into registers
        uint4 ra0 = *(const uint4*)Ap0;
        uint4 ra1 = *(const uint4*)Ap1;
        uint4 rb0, rb1;
        if (!diag) { rb0 = *(const uint4*)Bp0; rb1 = *(const uint4*)Bp1; }

        for (int k = 0; k < 16; ++k) {
            const int buf = k & 1;
            *(uint4*)((char*)Alds[buf] + e0 * 16) = ra0;
            *(uint4*)((char*)Alds[buf] + e1 * 16) = ra1;
            if (!diag) {
                *(uint4*)((char*)Blds[buf] + e0 * 16) = rb0;
                *(uint4*)((char*)Blds[buf] + e1 * 16) = rb1;
            }
            if (k < 15) {
                const int off = (k + 1) * 32;
                ra0 = *(const uint4*)(Ap0 + off);
                ra1 = *(const uint4*)(Ap1 + off);
                if (!diag) {
                    rb0 = *(const uint4*)(Bp0 + off);
                    rb1 = *(const uint4*)(Bp1 + off);
                }
            }
            wg_barrier_lgkm();   // ds_writes visible; prefetch stays in flight
            const __bf16* Al = Alds[buf];
            const __bf16* Bl = diag ? Alds[buf] : Blds[buf];
            bf16x8 av[4], bv[4];
#pragma unroll
            for (int mt = 0; mt < 4; ++mt) {
                const int row = wy * 64 + mt * 16 + lr;
                const int slot = (kg ^ (row & 3) ^ ((row >> 2) & 3)) & 3;
                av[mt] = *(const bf16x8*)(Al + row * 32 + slot * 8);
            }
#pragma unroll
            for (int nt = 0; nt < 4; ++nt) {
                const int row = wx * 64 + nt * 16 + lr;
                const int slot = (kg ^ (row & 3) ^ ((row >> 2) & 3)) & 3;
                bv[nt] = *(const bf16x8*)(Bl + row * 32 + slot * 8);
            }
#pragma unroll
            for (int mt = 0; mt < 4; ++mt)
#pragma unroll
                for (int nt = 0; nt < 4; ++nt)
                    acc[mt][nt] = __builtin_amdgcn_mfma_f32_16x16x32_bf16(av[mt], bv[nt], acc[mt][nt], 0, 0, 0);
        }

        if (isCE) {
            // ---- CE epilogue: log-softmax over 128 cols, pick col y[i] ----
            int jn[4]; float bb[4];
#pragma unroll
            for (int nt = 0; nt < 4; ++nt) { jn[nt] = wx * 64 + nt * 16 + lr; bb[nt] = b[jn[nt]]; }
#pragma unroll
            for (int mt = 0; mt < 4; ++mt)
#pragma unroll
                for (int r = 0; r < 4; ++r) {
                    float m = acc[mt][0][r] + bb[0];
#pragma unroll
                    for (int nt = 1; nt < 4; ++nt) m = fmaxf(m, acc[mt][nt][r] + bb[nt]);
                    m = fmaxf(m, __shfl_xor(m, 1));
                    m = fmaxf(m, __shfl_xor(m, 2));
                    m = fmaxf(m, __shfl_xor(m, 4));
                    m = fmaxf(m, __shfl_xor(m, 8));
                    if (lr == 0) rmax[wy * 64 + mt * 16 + kg * 4 + r][wx] = m;
                }
            __syncthreads();
            float mrow[4][4];
#pragma unroll
            for (int mt = 0; mt < 4; ++mt)
#pragma unroll
                for (int r = 0; r < 4; ++r) {
                    const int ri = wy * 64 + mt * 16 + kg * 4 + r;
                    mrow[mt][r] = fmaxf(rmax[ri][0], rmax[ri][1]);
                    float s = 0.f;
#pragma unroll
                    for (int nt = 0; nt < 4; ++nt) s += expf(acc[mt][nt][r] + bb[nt] - mrow[mt][r]);
                    s += __shfl_xor(s, 1);
                    s += __shfl_xor(s, 2);
                    s += __shfl_xor(s, 4);
                    s += __shfl_xor(s, 8);
                    if (lr == 0) rsum[ri][wx] = s;
                }
            __syncthreads();
#pragma unroll
            for (int mt = 0; mt < 4; ++mt)
#pragma unroll
                for (int r = 0; r < 4; ++r) {
                    const int ri = wy * 64 + mt * 16 + kg * 4 + r;
                    const int i = bi + ri;
                    const float s = rsum[ri][0] + rsum[ri][1];
                    const int yi = y[i];
#pragma unroll
                    for (int nt = 0; nt < 4; ++nt)
                        if (jn[nt] == yi)
                            lossrow[i] = -(acc[mt][nt][r] + bb[nt] - mrow[mt][r] - logf(s));
                }
        } else {
            // ---- count epilogue (symmetric) ----
            const float sq0 = sq[0];
            int jn[4]; float sqj[4], thrj[4];
#pragma unroll
            for (int nt = 0; nt < 4; ++nt) {
                jn[nt] = bj + wx * 64 + nt * 16 + lr;
                sqj[nt] = sq[jn[nt]];
                thrj[nt] = sq0 - 2.0f * dot0[jn[nt]];
            }
            unsigned cj[4] = {0u, 0u, 0u, 0u};
#pragma unroll
            for (int mt = 0; mt < 4; ++mt)
#pragma unroll
                for (int r = 0; r < 4; ++r) {
                    const int i = bi + wy * 64 + mt * 16 + kg * 4 + r;
                    const float thri = sq0 - 2.0f * dot0[i];
                    const float sqi = sq[i];
                    unsigned ci = 0;
                    if (diag) {
#pragma unroll
                        for (int nt = 0; nt < 4; ++nt) {
                            const float d = acc[mt][nt][r];
                            const int j = jn[nt];
                            if (sqj[nt] - 2.0f * d < thri && j != i && j != 0) ++ci;
                        }
                    } else {
                        // bj > bi: j >= 128 > 0 and i < bj <= j, no guards needed
#pragma unroll
                        for (int nt = 0; nt < 4; ++nt) {
                            const float d = acc[mt][nt][r];
                            if (sqj[nt] - 2.0f * d < thri) ++ci;
                            if (sqi - 2.0f * d < thrj[nt] && i != 0) ++cj[nt];
                        }
                    }
                    ci += __shfl_xor((int)ci, 1);
                    ci += __shfl_xor((int)ci, 2);
                    ci += __shfl_xor((int)ci, 4);
                    ci += __shfl_xor((int)ci, 8);
                    if (lr == 0 && ci) atomicAdd(&cnt[i], ci);
                }
            if (!diag) {
#pragma unroll
                for (int nt = 0; nt < 4; ++nt) {
                    unsigned v = cj[nt];
                    v += __shfl_xor((int)v, 16);
                    v += __shfl_xor((int)v, 32);
                    if (l < 16 && v) atomicAdd(&cnt[jn[nt]], v);
                }
            }
        }
    }
}

// ---------------------------------------------------------------------------
// finalize: out = mean(lossrow) + ALPHA * sum_{i>0, y_i==y_0, cnt[i]<=1} ||Y_i - Y_0||
// ---------------------------------------------------------------------------
__global__ __launch_bounds__(1024) void final_kernel(const float* __restrict__ lossrow,
                                                     const unsigned* __restrict__ cnt,
                                                     const int* __restrict__ y,
                                                     const float* __restrict__ Y,
                                                     float* __restrict__ out) {
    const int t = threadIdx.x;
    const int y0 = y[0];
    double ls = 0.0, rs = 0.0;
    for (int i = t; i < N; i += 1024) {
        ls += (double)lossrow[i];
        if (i > 0 && y[i] == y0 && cnt[i] <= 1u) {
            float d2 = 0.f;
            for (int c = 0; c < C; ++c) {
                float d = Y[(size_t)i * C + c] - Y[c];
                d2 += d * d;
            }
            rs += (double)sqrtf(fmaxf(d2, 0.f));
        }
    }
    for (int o = 32; o; o >>= 1) {
        ls += __shfl_down(ls, o);
        rs += __shfl_down(rs, o);
    }
    __shared__ double dl[16], dr[16];
    if ((t & 63) == 0) { dl[t >> 6] = ls; dr[t >> 6] = rs; }
    __syncthreads();
    if (t == 0) {
        double L = 0.0, R = 0.0;
        for (int k = 0; k < 16; ++k) { L += dl[k]; R += dr[k]; }
        out[0] = (float)(L / (double)N + (double)ALPHA * R);
    }
}

// ---------------------------------------------------------------------------
extern "C" void kernel_launch(void* const* d_in, const int* in_sizes, int n_in,
                              void* d_out, int out_size, void* d_ws, size_t ws_size,
                              hipStream_t stream) {
    const float* x  = (const float*)d_in[0];   // (N, D)
    const int*   y  = (const int*)d_in[1];     // (N,)
    const float* Y  = (const float*)d_in[2];   // (N, C)
    const float* W  = (const float*)d_in[3];   // (D, C)
    const float* b  = (const float*)d_in[4];   // (C,)
    float* out = (float*)d_out;

    float* wsf      = (float*)d_ws;
    float* lossrow  = wsf;                       // N f32
    float* sq       = wsf + N;                   // N f32
    float* dot0     = wsf + 2 * N;               // N f32
    unsigned* cnt   = (unsigned*)(wsf + 3 * N);  // N u32
    __bf16* xb      = (__bf16*)(wsf + 4 * N);    // N*D bf16 (4 MB)
    __bf16* Wtb     = (__bf16*)((char*)xb + (size_t)N * D * 2); // C*D bf16
    unsigned* qhead = (unsigned*)((char*)Wtb + (size_t)C * D * 2);

    prep_kernel<<<N / 4 + 256, 256, 0, stream>>>(x, sq, dot0, xb, W, Wtb, cnt, qhead);
    fused_mfma<<<GRID_FUSED, 256, 0, stream>>>(xb, Wtb, sq, dot0, y, b, cnt, lossrow, qhead);
    final_kernel<<<1, 1024, 0, stream>>>(lossrow, cnt, y, Y, out);
}

// Round 8
// 107.716 us; speedup vs baseline: 1.1057x; 1.1057x over previous
//
#include <hip/hip_runtime.h>
#include <math.h>
#include <stdint.h>

#define N 4096
#define D 512
#define C 128
#define ALPHA 0.0005
#define NCOUNT 1056     // sum over 64 strips of (32 - strip/2) col-tiles
#define NCE 64          // 64-row CE tiles
#define NBLK (NCOUNT + NCE)

typedef __bf16 bf16x8 __attribute__((ext_vector_type(8)));
typedef float f32x4 __attribute__((ext_vector_type(4)));

// async global->LDS, 16B per lane. LDS dest is wave-uniform base + lane*16.
__device__ __forceinline__ void async16(const void* g, void* l) {
    __builtin_amdgcn_global_load_lds(
        reinterpret_cast<const __attribute__((address_space(1))) uint32_t*>(
            reinterpret_cast<uintptr_t>(g)),
        reinterpret_cast<__attribute__((address_space(3))) uint32_t*>(
            reinterpret_cast<uintptr_t>(l)),
        16, 0, 0);
}

// ---------------------------------------------------------------------------
// prep: blocks [0,N/4)        : 4 rows/block, 1 wave/row: sq, dot0, xb, cnt=0
//       blocks [N/4,N/4+256)  : Wtb[n][k] = bf16(W[k][n]); one thread zeroes
//                               the finalize accumulators.
// ---------------------------------------------------------------------------
__global__ __launch_bounds__(256) void prep_kernel(const float* __restrict__ x,
                                                   float* __restrict__ sq,
                                                   float* __restrict__ dot0,
                                                   __bf16* __restrict__ xb,
                                                   const float* __restrict__ W,
                                                   __bf16* __restrict__ Wtb,
                                                   unsigned* __restrict__ cnt,
                                                   double* __restrict__ dacc,
                                                   unsigned* __restrict__ done) {
    if (blockIdx.x >= N / 4) {
        const int tid = (blockIdx.x - N / 4) * 256 + threadIdx.x;  // 0..D*C-1
        const int k = tid >> 7;
        const int n = tid & 127;
        Wtb[(size_t)n * D + k] = (__bf16)W[tid];
        if (blockIdx.x == N / 4 && threadIdx.x == 0) {
            dacc[0] = 0.0; dacc[1] = 0.0; *done = 0u;
        }
        return;
    }
    const int i = blockIdx.x * 4 + (threadIdx.x >> 6);
    const int l = threadIdx.x & 63;
    const float* xp = x + (size_t)i * D + l * 8;
    const float4 v0 = *(const float4*)(xp);
    const float4 v1 = *(const float4*)(xp + 4);
    const float4 u0 = *(const float4*)(x + l * 8);
    const float4 u1 = *(const float4*)(x + l * 8 + 4);
    float s1 = v0.x * v0.x + v0.y * v0.y + v0.z * v0.z + v0.w * v0.w
             + v1.x * v1.x + v1.y * v1.y + v1.z * v1.z + v1.w * v1.w;
    float s2 = v0.x * u0.x + v0.y * u0.y + v0.z * u0.z + v0.w * u0.w
             + v1.x * u1.x + v1.y * u1.y + v1.z * u1.z + v1.w * u1.w;
    bf16x8 o;
    o[0] = (__bf16)v0.x; o[1] = (__bf16)v0.y; o[2] = (__bf16)v0.z; o[3] = (__bf16)v0.w;
    o[4] = (__bf16)v1.x; o[5] = (__bf16)v1.y; o[6] = (__bf16)v1.z; o[7] = (__bf16)v1.w;
    *(bf16x8*)(xb + (size_t)i * D + l * 8) = o;
    for (int off = 32; off; off >>= 1) {
        s1 += __shfl_down(s1, off);
        s2 += __shfl_down(s2, off);
    }
    if (l == 0) { sq[i] = s1; dot0[i] = s2; cnt[i] = 0u; }
}

// ---------------------------------------------------------------------------
// fused_mfma: 64x128 tiles.
//   count tiles: strip si (64 rows at bi=64*si), col tile cj (128 cols at
//     bj=128*cj), cj >= si/2. cj==si/2 is the "edge" tile containing the
//     diagonal: count with guards (j!=i, j!=0), no col-update (transposed
//     entries appear in this or the adjacent strip's edge tile). cj>si/2 is
//     strictly upper: row-update unguarded + col-update (i!=0 guard).
//   CE tiles: 64 rows x 128 logits, log-softmax, pick y[i].
// Staging: R2-proven global_load_lds BK=32 single-buffer 2-barrier loop;
// XOR slot swizzle keeps global reads coalesced and ds_read_b128 ~conflict-free.
// 4 waves: wy=rows half (32), wx=cols half (64); 2x4 MFMA frags per wave.
// ---------------------------------------------------------------------------
__global__ __launch_bounds__(256) void fused_mfma(const __bf16* __restrict__ xb,
                                                  const __bf16* __restrict__ Wtb,
                                                  const float* __restrict__ sq,
                                                  const float* __restrict__ dot0,
                                                  const int* __restrict__ y,
                                                  const float* __restrict__ b,
                                                  unsigned* __restrict__ cnt,
                                                  float* __restrict__ lossrow) {
    __shared__ __bf16 Alds[64 * 32];
    __shared__ __bf16 Blds[128 * 32];
    __shared__ float rmax[64][2];
    __shared__ float rsum[64][2];
    const int t = threadIdx.x;
    const int w = t >> 6, l = t & 63;
    const int wy = w >> 1, wx = w & 1;
    const int kg = l >> 4, lr = l & 15;

    const int bid = (int)blockIdx.x;
    const bool isCE = (bid >= NCOUNT);
    int bi, bj;
    bool edge = false;
    const __bf16* Bbase;
    if (isCE) {
        bi = (bid - NCOUNT) * 64;
        bj = 0;
        Bbase = Wtb;
    } else {
        int si = 0, rem = bid;
        while (rem >= 32 - (si >> 1)) { rem -= 32 - (si >> 1); ++si; }
        const int cj = (si >> 1) + rem;
        bi = si * 64;
        bj = cj * 128;
        edge = (rem == 0);
        Bbase = xb + (size_t)bj * D;
    }
    const __bf16* Abase = xb + (size_t)bi * D;

    f32x4 acc[2][4];
    const f32x4 zero = {0.f, 0.f, 0.f, 0.f};
#pragma unroll
    for (int mt = 0; mt < 2; ++mt)
#pragma unroll
        for (int nt = 0; nt < 4; ++nt) acc[mt][nt] = zero;

    // staging geometry. A: 256 x 16B chunks (1/thread); B: 512 (2/thread).
    const int rA = t >> 2, cA = t & 3;
    const int scA = (cA ^ (rA & 3) ^ ((rA >> 2) & 3)) & 3;
    const int eB0 = t, eB1 = t + 256;
    const int rB0 = eB0 >> 2, cB0 = eB0 & 3;
    const int rB1 = eB1 >> 2, cB1 = eB1 & 3;
    const int scB0 = (cB0 ^ (rB0 & 3) ^ ((rB0 >> 2) & 3)) & 3;
    const int scB1 = (cB1 ^ (rB1 & 3) ^ ((rB1 >> 2) & 3)) & 3;

    for (int kc = 0; kc < D; kc += 32) {
        __syncthreads();   // previous iteration's frag reads done
        async16(Abase + (size_t)rA * D + kc + scA * 8, (char*)Alds + t * 16);
        async16(Bbase + (size_t)rB0 * D + kc + scB0 * 8, (char*)Blds + eB0 * 16);
        async16(Bbase + (size_t)rB1 * D + kc + scB1 * 8, (char*)Blds + eB1 * 16);
        __syncthreads();   // staging visible
        bf16x8 av[2], bv[4];
#pragma unroll
        for (int mt = 0; mt < 2; ++mt) {
            const int row = wy * 32 + mt * 16 + lr;
            const int slot = (kg ^ (row & 3) ^ ((row >> 2) & 3)) & 3;
            av[mt] = *(const bf16x8*)(Alds + row * 32 + slot * 8);
        }
#pragma unroll
        for (int nt = 0; nt < 4; ++nt) {
            const int row = wx * 64 + nt * 16 + lr;
            const int slot = (kg ^ (row & 3) ^ ((row >> 2) & 3)) & 3;
            bv[nt] = *(const bf16x8*)(Blds + row * 32 + slot * 8);
        }
#pragma unroll
        for (int mt = 0; mt < 2; ++mt)
#pragma unroll
            for (int nt = 0; nt < 4; ++nt)
                acc[mt][nt] = __builtin_amdgcn_mfma_f32_16x16x32_bf16(av[mt], bv[nt], acc[mt][nt], 0, 0, 0);
    }

    if (isCE) {
        // ---- CE epilogue: log-softmax over 128 cols, pick col y[i] ----
        int jn[4]; float bb[4];
#pragma unroll
        for (int nt = 0; nt < 4; ++nt) { jn[nt] = wx * 64 + nt * 16 + lr; bb[nt] = b[jn[nt]]; }
#pragma unroll
        for (int mt = 0; mt < 2; ++mt)
#pragma unroll
            for (int r = 0; r < 4; ++r) {
                float m = acc[mt][0][r] + bb[0];
#pragma unroll
                for (int nt = 1; nt < 4; ++nt) m = fmaxf(m, acc[mt][nt][r] + bb[nt]);
                m = fmaxf(m, __shfl_xor(m, 1));
                m = fmaxf(m, __shfl_xor(m, 2));
                m = fmaxf(m, __shfl_xor(m, 4));
                m = fmaxf(m, __shfl_xor(m, 8));
                if (lr == 0) rmax[wy * 32 + mt * 16 + kg * 4 + r][wx] = m;
            }
        __syncthreads();
        float mrow[2][4];
#pragma unroll
        for (int mt = 0; mt < 2; ++mt)
#pragma unroll
            for (int r = 0; r < 4; ++r) {
                const int ri = wy * 32 + mt * 16 + kg * 4 + r;
                mrow[mt][r] = fmaxf(rmax[ri][0], rmax[ri][1]);
                float s = 0.f;
#pragma unroll
                for (int nt = 0; nt < 4; ++nt) s += expf(acc[mt][nt][r] + bb[nt] - mrow[mt][r]);
                s += __shfl_xor(s, 1);
                s += __shfl_xor(s, 2);
                s += __shfl_xor(s, 4);
                s += __shfl_xor(s, 8);
                if (lr == 0) rsum[ri][wx] = s;
            }
        __syncthreads();
#pragma unroll
        for (int mt = 0; mt < 2; ++mt)
#pragma unroll
            for (int r = 0; r < 4; ++r) {
                const int ri = wy * 32 + mt * 16 + kg * 4 + r;
                const int i = bi + ri;
                const float s = rsum[ri][0] + rsum[ri][1];
                const int yi = y[i];
#pragma unroll
                for (int nt = 0; nt < 4; ++nt)
                    if (jn[nt] == yi)
                        lossrow[i] = -(acc[mt][nt][r] + bb[nt] - mrow[mt][r] - logf(s));
            }
    } else {
        // ---- count epilogue ----
        const float sq0 = sq[0];
        int jn[4]; float sqj[4], thrj[4];
#pragma unroll
        for (int nt = 0; nt < 4; ++nt) {
            jn[nt] = bj + wx * 64 + nt * 16 + lr;
            sqj[nt] = sq[jn[nt]];
            thrj[nt] = sq0 - 2.0f * dot0[jn[nt]];
        }
        unsigned cj[4] = {0u, 0u, 0u, 0u};
#pragma unroll
        for (int mt = 0; mt < 2; ++mt)
#pragma unroll
            for (int r = 0; r < 4; ++r) {
                const int i = bi + wy * 32 + mt * 16 + kg * 4 + r;
                const float thri = sq0 - 2.0f * dot0[i];
                const float sqi = sq[i];
                unsigned ci = 0;
                if (edge) {
#pragma unroll
                    for (int nt = 0; nt < 4; ++nt) {
                        const float d = acc[mt][nt][r];
                        const int j = jn[nt];
                        if (sqj[nt] - 2.0f * d < thri && j != i && j != 0) ++ci;
                    }
                } else {
                    // strictly upper: j >= bi+64 > i and j >= 128 > 0
#pragma unroll
                    for (int nt = 0; nt < 4; ++nt) {
                        const float d = acc[mt][nt][r];
                        if (sqj[nt] - 2.0f * d < thri) ++ci;
                        if (sqi - 2.0f * d < thrj[nt] && i != 0) ++cj[nt];
                    }
                }
                ci += __shfl_xor((int)ci, 1);
                ci += __shfl_xor((int)ci, 2);
                ci += __shfl_xor((int)ci, 4);
                ci += __shfl_xor((int)ci, 8);
                if (lr == 0 && ci) atomicAdd(&cnt[i], ci);
            }
        if (!edge) {
#pragma unroll
            for (int nt = 0; nt < 4; ++nt) {
                unsigned v = cj[nt];
                v += __shfl_xor((int)v, 16);
                v += __shfl_xor((int)v, 32);
                if (l < 16 && v) atomicAdd(&cnt[jn[nt]], v);
            }
        }
    }
}

// ---------------------------------------------------------------------------
// reg_kernel: 32 blocks x 128 rows, 2 threads/row (64 cols each).
// Partial double sums -> atomicAdd; last block writes out.
// ---------------------------------------------------------------------------
__global__ __launch_bounds__(256) void reg_kernel(const float* __restrict__ lossrow,
                                                  const unsigned* __restrict__ cnt,
                                                  const int* __restrict__ y,
                                                  const float* __restrict__ Y,
                                                  double* __restrict__ dacc,
                                                  unsigned* __restrict__ done,
                                                  float* __restrict__ out) {
    const int t = threadIdx.x;
    const int i = blockIdx.x * 128 + (t >> 1);
    const int half = t & 1;
    const int y0 = y[0];

    const float4* yr = (const float4*)(Y + (size_t)i * C + half * 64);
    const float4* yz = (const float4*)(Y + half * 64);
    float d2 = 0.f;
#pragma unroll
    for (int c = 0; c < 16; ++c) {
        const float4 a = yr[c];
        const float4 bb = yz[c];
        const float dx = a.x - bb.x, dy = a.y - bb.y, dz = a.z - bb.z, dw = a.w - bb.w;
        d2 += dx * dx + dy * dy + dz * dz + dw * dw;
    }
    d2 += __shfl_xor(d2, 1);

    double ls = 0.0, rs = 0.0;
    if (half == 0) {
        ls = (double)lossrow[i];
        if (i > 0 && y[i] == y0 && cnt[i] <= 1u)
            rs = sqrt((double)fmaxf(d2, 0.f));
    }
    for (int o = 32; o; o >>= 1) {
        ls += __shfl_down(ls, o);
        rs += __shfl_down(rs, o);
    }
    __shared__ double dl[4], dr[4];
    if ((t & 63) == 0) { dl[t >> 6] = ls; dr[t >> 6] = rs; }
    __syncthreads();
    if (t == 0) {
        atomicAdd(&dacc[0], dl[0] + dl[1] + dl[2] + dl[3]);
        atomicAdd(&dacc[1], dr[0] + dr[1] + dr[2] + dr[3]);
        __threadfence();
        if (atomicAdd(done, 1u) == 31u) {
            const double L = atomicAdd(&dacc[0], 0.0);
            const double R = atomicAdd(&dacc[1], 0.0);
            out[0] = (float)(L / (double)N + ALPHA * R);
        }
    }
}

// ---------------------------------------------------------------------------
extern "C" void kernel_launch(void* const* d_in, const int* in_sizes, int n_in,
                              void* d_out, int out_size, void* d_ws, size_t ws_size,
                              hipStream_t stream) {
    const float* x  = (const float*)d_in[0];   // (N, D)
    const int*   y  = (const int*)d_in[1];     // (N,)
    const float* Y  = (const float*)d_in[2];   // (N, C)
    const float* W  = (const float*)d_in[3];   // (D, C)
    const float* b  = (const float*)d_in[4];   // (C,)
    float* out = (float*)d_out;

    float* wsf      = (float*)d_ws;
    float* lossrow  = wsf;                       // N f32
    float* sq       = wsf + N;                   // N f32
    float* dot0     = wsf + 2 * N;               // N f32
    unsigned* cnt   = (unsigned*)(wsf + 3 * N);  // N u32
    __bf16* xb      = (__bf16*)(wsf + 4 * N);    // N*D bf16 (4 MB)
    __bf16* Wtb     = (__bf16*)((char*)xb + (size_t)N * D * 2); // C*D bf16
    double* dacc    = (double*)((char*)Wtb + (size_t)C * D * 2);
    unsigned* done  = (unsigned*)(dacc + 2);

    prep_kernel<<<N / 4 + 256, 256, 0, stream>>>(x, sq, dot0, xb, W, Wtb, cnt, dacc, done);
    fused_mfma<<<NBLK, 256, 0, stream>>>(xb, Wtb, sq, dot0, y, b, cnt, lossrow);
    reg_kernel<<<32, 256, 0, stream>>>(lossrow, cnt, y, Y, dacc, done, out);
}